// Round 5
// baseline (159.797 us; speedup 1.0000x reference)
//
#include <hip/hip_runtime.h>
#include <math.h>

// Round 5: no-LDS-staging attention. K/V fragments are contiguous 16B global
// loads (identical across waves -> L1/L2-served); LDS holds only the per-wave
// P buffer -> 4 blocks/CU, ZERO barriers in the main loop. 16 q-rows/wave,
// 64-row blocks, grid 1024. k_kv: LDS-broadcast weights, 16 pos/block, grid 1024.

#define B_SZ 16
#define C_IN 64
#define C_INT 32
#define HW 4096
#define NKV 1024
#define CHK 128
#define NCHUNK 8
#define PSTR 136   // P row stride (ushorts): 128 kv + 8 pad (16B-aligned rows)
#define QSTR 36    // sQf / sy row stride (floats)

typedef __attribute__((ext_vector_type(8))) short bfrag;
typedef __attribute__((ext_vector_type(4))) float f32x4;

static __device__ __forceinline__ ushort f2bf(float v) {
  union { float f; uint u; } c; c.f = v;
  uint b = c.u + 0x7FFFu + ((c.u >> 16) & 1u);
  return (ushort)(b >> 16);
}
static __device__ __forceinline__ float bf2f(ushort h) {
  union { uint u; float f; } c; c.u = (uint)h << 16; return c.f;
}

// -------- kernel 1: phi & origin conv + maxpool -> Khi/Klo, Vt --------
// Block = (bb, g): 16 pooled positions, both sels. 256 thr = sel(2) x oh(2) x d(4) x mp(16).
__global__ __launch_bounds__(256, 4) void k_kv(
    const float* __restrict__ x,
    const float* __restrict__ wphi, const float* __restrict__ bphi,
    const float* __restrict__ worg, const float* __restrict__ borg,
    ushort* __restrict__ Khi, ushort* __restrict__ Klo, ushort* __restrict__ Vt) {
  __shared__ __align__(16) float ws[2][32][64];     // 16384 B, broadcast reads
  __shared__ float bs[2][32];
  __shared__ float red[2][4][16][33];               // 16896 B
  int t = threadIdx.x;
  for (int i = t; i < 2 * 32 * 64; i += 256) {
    int s = i >> 11, r = i & 2047;
    (&ws[0][0][0])[i] = s ? worg[r] : wphi[r];
  }
  if (t < 64) (&bs[0][0])[t] = (t < 32) ? bphi[t] : borg[t - 32];

  int bb = blockIdx.x >> 6;
  int g  = blockIdx.x & 63;                // 64 groups of 16 pooled positions
  int sel = t >> 7;
  int sub = t & 127;
  int oh = sub >> 6, rest = sub & 63;
  int d = rest >> 4, mp = rest & 15;
  int mpg = g * 16 + mp;
  int py = mpg >> 5, px = mpg & 31;
  int pix = (py << 7) + (px << 1) + ((d >> 1) << 6) + (d & 1);
  const float* xp = x + ((size_t)bb << 18) + pix;
  __syncthreads();

  float acc[16];
  #pragma unroll
  for (int o = 0; o < 16; ++o) acc[o] = bs[sel][oh * 16 + o];
  for (int cq = 0; cq < 16; ++cq) {
    float xv0 = xp[(size_t)(4*cq+0) << 12];
    float xv1 = xp[(size_t)(4*cq+1) << 12];
    float xv2 = xp[(size_t)(4*cq+2) << 12];
    float xv3 = xp[(size_t)(4*cq+3) << 12];
    #pragma unroll
    for (int o = 0; o < 16; ++o) {
      const float4 w4 = *(const float4*)&ws[sel][oh * 16 + o][cq * 4];  // broadcast
      acc[o] += xv0*w4.x + xv1*w4.y + xv2*w4.z + xv3*w4.w;
    }
  }
  #pragma unroll
  for (int o = 0; o < 16; ++o) red[sel][d][mp][oh * 16 + o] = acc[o];
  __syncthreads();

  for (int f = t; f < 1024; f += 256) {          // 2 sel x 16 mp x 32 o
    int sw = f >> 9, rem = f & 511;
    int mo = rem >> 5, o = rem & 31;
    float v = fmaxf(fmaxf(red[sw][0][mo][o], red[sw][1][mo][o]),
                    fmaxf(red[sw][2][mo][o], red[sw][3][mo][o]));
    if (sw == 0) {
      ushort hb = f2bf(v);
      size_t idx = ((size_t)bb * NKV + g * 16 + mo) * 32 + o;
      Khi[idx] = hb;
      Klo[idx] = f2bf(v - bf2f(hb));
    } else {
      Vt[((size_t)bb * 32 + o) * NKV + g * 16 + mo] = f2bf(v);
    }
  }
}

// -------- kernel 2: fused theta-conv + MFMA flash attention + W-conv --------
// 256 thr = 4 waves x 16 q-rows; block = 64 rows; grid = 16*64 = 1024.
// No barriers in the main loop; K/V frags loaded directly from global.
__global__ __launch_bounds__(256, 4) void k_attn(
    const float* __restrict__ x,
    const float* __restrict__ wT, const float* __restrict__ bT,
    const ushort* __restrict__ Khi, const ushort* __restrict__ Klo,
    const ushort* __restrict__ Vt,
    const float* __restrict__ wW, const float* __restrict__ bW,
    float* __restrict__ z) {
  __shared__ __align__(16) ushort sPQ[4 * 16 * PSTR];   // 17408 B (P; reused as sQf/sy)

  int t = threadIdx.x;
  int wave = t >> 6, lane = t & 63, l15 = lane & 15, quad = lane >> 4;
  int bb = blockIdx.x >> 6;
  int p0 = (blockIdx.x & 63) << 6;      // 64 rows per block

  // ---- prologue: theta conv, 64 pixels x 32 ch; wave-uniform ch-group -> s_load weights
  float* sQf = (float*)sPQ;
  {
    int pl = t & 63;
    int oq = __builtin_amdgcn_readfirstlane(t >> 6);    // 4 groups of 8 out-ch
    const float* xp = x + ((size_t)bb << 18) + p0 + pl;
    float acc[8];
    #pragma unroll
    for (int o = 0; o < 8; ++o) acc[o] = bT[oq * 8 + o];
    for (int cq = 0; cq < 16; ++cq) {
      float xv0 = xp[(size_t)(4*cq+0) << 12];
      float xv1 = xp[(size_t)(4*cq+1) << 12];
      float xv2 = xp[(size_t)(4*cq+2) << 12];
      float xv3 = xp[(size_t)(4*cq+3) << 12];
      #pragma unroll
      for (int o = 0; o < 8; ++o) {
        const float4 w4 = *(const float4*)&wT[(oq*8+o) * C_IN + 4*cq];  // s_load
        acc[o] += xv0*w4.x + xv1*w4.y + xv2*w4.z + xv3*w4.w;
      }
    }
    *(float4*)&sQf[pl * QSTR + oq * 8 + 0] = make_float4(acc[0], acc[1], acc[2], acc[3]);
    *(float4*)&sQf[pl * QSTR + oq * 8 + 4] = make_float4(acc[4], acc[5], acc[6], acc[7]);
  }
  __syncthreads();

  // ---- Q B-frags (B[k=quad*8+j][n=l15]), hi/lo split
  bfrag aQh, aQl;
  {
    const float* qrow = &sQf[(wave * 16 + l15) * QSTR + quad * 8];
    #pragma unroll
    for (int k = 0; k < 8; ++k) {
      float v = qrow[k];
      ushort hb = f2bf(v);
      aQh[k] = (short)hb;
      aQl[k] = (short)f2bf(v - bf2f(hb));
    }
  }
  __syncthreads();   // sQf dead -> region becomes P buffers

  f32x4 accO[2], accS;
  accO[0] = (f32x4){0.f,0.f,0.f,0.f};
  accO[1] = (f32x4){0.f,0.f,0.f,0.f};
  accS    = (f32x4){0.f,0.f,0.f,0.f};
  bfrag vones;
  #pragma unroll
  for (int i = 0; i < 8; ++i) vones[i] = (short)0x3F80;

  const ushort* Kh_g = Khi + (size_t)bb * NKV * 32;
  const ushort* Kl_g = Klo + (size_t)bb * NKV * 32;
  const ushort* Vt_g = Vt  + (size_t)bb * 32 * NKV;
  ushort* myP = sPQ + wave * 16 * PSTR;

  for (int c = 0; c < NCHUNK; ++c) {
    int k0 = c * CHK;

    // ---- K frags: contiguous 16B global loads (A[m=kv(l15)][k=ch(quad*8+j)])
    bfrag kh[8], kl[8];
    #pragma unroll
    for (int tt = 0; tt < 8; ++tt) {
      kh[tt] = *(const bfrag*)(Kh_g + (size_t)(k0 + tt*16 + l15) * 32 + quad * 8);
      kl[tt] = *(const bfrag*)(Kl_g + (size_t)(k0 + tt*16 + l15) * 32 + quad * 8);
    }

    // ---- S^T = K.Q^T -> exp -> P (bf16, per-wave LDS buffer, no barrier)
    #pragma unroll
    for (int tt = 0; tt < 8; ++tt) {
      f32x4 s = (f32x4){0.f,0.f,0.f,0.f};
      s = __builtin_amdgcn_mfma_f32_16x16x32_bf16(kh[tt], aQh, s, 0, 0, 0);
      s = __builtin_amdgcn_mfma_f32_16x16x32_bf16(kh[tt], aQl, s, 0, 0, 0);
      s = __builtin_amdgcn_mfma_f32_16x16x32_bf16(kl[tt], aQh, s, 0, 0, 0);
      float e0 = __expf(s[0]), e1 = __expf(s[1]);
      float e2 = __expf(s[2]), e3 = __expf(s[3]);
      uint2 pk;
      pk.x = (__float_as_uint(e0) >> 16) | (__float_as_uint(e1) & 0xFFFF0000u);
      pk.y = (__float_as_uint(e2) >> 16) | (__float_as_uint(e3) & 0xFFFF0000u);
      *(uint2*)&myP[l15 * PSTR + tt*16 + quad*4] = pk;   // P[q=l15][kv]
    }

    // ---- V frags direct from global (B[k=kv(quad*8+j)][n=ch(l15)])
    bfrag vb[4][2];
    #pragma unroll
    for (int ks = 0; ks < 4; ++ks) {
      vb[ks][0] = *(const bfrag*)(Vt_g + (size_t)(l15)      * NKV + k0 + ks*32 + quad*8);
      vb[ks][1] = *(const bfrag*)(Vt_g + (size_t)(16 + l15) * NKV + k0 + ks*32 + quad*8);
    }

    // ---- O += P.V ; row-sums via ones-MFMA
    #pragma unroll
    for (int ks = 0; ks < 4; ++ks) {
      bfrag a = *(const bfrag*)&myP[l15 * PSTR + ks*32 + quad*8];
      accO[0] = __builtin_amdgcn_mfma_f32_16x16x32_bf16(a, vb[ks][0], accO[0], 0, 0, 0);
      accO[1] = __builtin_amdgcn_mfma_f32_16x16x32_bf16(a, vb[ks][1], accO[1], 0, 0, 0);
      accS    = __builtin_amdgcn_mfma_f32_16x16x32_bf16(a, vones,     accS,    0, 0, 0);
    }
  }

  __syncthreads();   // all waves done with P -> reuse as sy
  float* sy = (float*)sPQ;
  #pragma unroll
  for (int r = 0; r < 4; ++r) {
    float inv = 1.0f / accS[r];
    sy[(wave*16 + quad*4 + r) * QSTR + l15]      = accO[0][r] * inv;
    sy[(wave*16 + quad*4 + r) * QSTR + 16 + l15] = accO[1][r] * inv;
  }
  __syncthreads();

  // ---- z = W.y + bW + x  (wave-uniform out-ch group -> s_load weights)
  {
    int pl = t & 63;
    int oq = __builtin_amdgcn_readfirstlane(t >> 6);    // 4 groups of 16 out-ch
    float yv[C_INT];
    #pragma unroll
    for (int c4 = 0; c4 < 8; ++c4) {
      float4 f = *(const float4*)&sy[pl * QSTR + c4 * 4];
      yv[c4*4+0] = f.x; yv[c4*4+1] = f.y; yv[c4*4+2] = f.z; yv[c4*4+3] = f.w;
    }
    #pragma unroll
    for (int co = 0; co < 16; ++co) {
      int cout = oq * 16 + co;
      size_t zi = ((size_t)bb << 18) + ((size_t)cout << 12) + p0 + pl;
      float a = bW[cout] + x[zi];
      #pragma unroll
      for (int c4 = 0; c4 < 8; ++c4) {
        const float4 w4 = *(const float4*)&wW[cout * C_INT + c4 * 4];
        a += yv[c4*4+0]*w4.x + yv[c4*4+1]*w4.y + yv[c4*4+2]*w4.z + yv[c4*4+3]*w4.w;
      }
      z[zi] = a;
    }
  }
}

extern "C" void kernel_launch(void* const* d_in, const int* in_sizes, int n_in,
                              void* d_out, int out_size, void* d_ws, size_t ws_size,
                              hipStream_t stream) {
  const float* x   = (const float*)d_in[0];
  const float* w_o = (const float*)d_in[1];
  const float* b_o = (const float*)d_in[2];
  const float* w_t = (const float*)d_in[3];
  const float* b_t = (const float*)d_in[4];
  const float* w_p = (const float*)d_in[5];
  const float* b_p = (const float*)d_in[6];
  const float* w_W = (const float*)d_in[7];
  const float* b_W = (const float*)d_in[8];
  float* z = (float*)d_out;

  ushort* Khi = (ushort*)d_ws;                              // 16*1024*32
  ushort* Klo = Khi + (size_t)B_SZ * NKV * C_INT;
  ushort* Vtw = Klo + (size_t)B_SZ * NKV * C_INT;           // 16*32*1024

  k_kv<<<dim3(B_SZ * 64), dim3(256), 0, stream>>>(x, w_p, b_p, w_o, b_o, Khi, Klo, Vtw);
  k_attn<<<dim3(B_SZ * 64), dim3(256), 0, stream>>>(x, w_t, b_t, Khi, Klo, Vtw, w_W, b_W, z);
}